// Round 7
// baseline (508.427 us; speedup 1.0000x reference)
//
#include <hip/hip_runtime.h>
#include <math.h>

#define B   128
#define V   128000
#define WPR 4000        // V/32 mask words per row
#define PL  2048
#define OL  256
#define BPR 25          // blocks per row in heavy passes (25*5*1024 = 128000)
#define ITERS 5
#define R_SEL 256       // per-row gather target (>= max top_k + ties)
#define LCAP 4096       // per-row gathered-list capacity
#define FP16_TINY 6.103515625e-05f

// monotone float->uint key (ascending)
__device__ __forceinline__ unsigned key_of(float f) {
    unsigned u = __float_as_uint(f);
    unsigned m = (unsigned)(((int)u) >> 31) | 0x80000000u;
    return u ^ m;
}
__device__ __forceinline__ float key_inv(unsigned k) {
    unsigned u = (k & 0x80000000u) ? (k ^ 0x80000000u) : ~k;
    return __uint_as_float(u);
}

// Deterministic transform; contract(off) so every call site lowers identically.
__device__ __forceinline__ float xform(float x, int pm, int om,
                                       float rep, float pres, float temp) {
#pragma clang fp contract(off)
    float pen = (pm | om) ? rep : 1.0f;
    float l = (x > 0.0f) ? (x / pen) : (x * pen);
    if (om) l = l - pres;
    return l / temp;
}

__global__ __launch_bounds__(256) void k_zero(unsigned* __restrict__ p, int n) {
    int i = blockIdx.x * 256 + threadIdx.x;
    int stride = gridDim.x * 256;
    for (; i < n; i += stride) p[i] = 0u;
}

__global__ __launch_bounds__(256) void k_scatter(const int* __restrict__ ptok,
                                                 const int* __restrict__ otok,
                                                 unsigned* __restrict__ bitP,
                                                 unsigned* __restrict__ bitO) {
    int i = blockIdx.x * 256 + threadIdx.x;
    int np = B * PL;
    int total = np + B * OL;
    if (i >= total) return;
    if (i < np) {
        int r = i >> 11;
        int t = ptok[i];
        if ((unsigned)t < (unsigned)V)
            atomicOr(&bitP[r * WPR + (t >> 5)], 1u << (t & 31));
    } else {
        int j = i - np;
        int r = j >> 8;
        int t = otok[j];
        if ((unsigned)t < (unsigned)V)
            atomicOr(&bitO[r * WPR + (t >> 5)], 1u << (t & 31));
    }
}

// Mask outputs only — no logits needed.
__global__ __launch_bounds__(256) void k_masks(
    const unsigned* __restrict__ bitP, const unsigned* __restrict__ bitO,
    float* __restrict__ outPm, float* __restrict__ outOm)
{
    int r = blockIdx.y;
    int c0 = blockIdx.x * (ITERS * 1024);
    int t = threadIdx.x;
    const unsigned* bp = bitP + r * WPR;
    const unsigned* bo = bitO + r * WPR;
    float* pmrow = outPm + (size_t)r * V;
    float* omrow = outOm + (size_t)r * V;
#pragma unroll
    for (int it = 0; it < ITERS; it++) {
        int i = c0 + it * 1024 + t * 4;
        unsigned wp = bp[i >> 5], wo = bo[i >> 5];
        int sh = i & 31;
        float fp[4], fo[4];
#pragma unroll
        for (int j = 0; j < 4; j++) {
            fp[j] = (float)((wp >> (sh + j)) & 1);
            fo[j] = (float)((wo >> (sh + j)) & 1);
        }
        *(float4*)(pmrow + i) = make_float4(fp[0], fp[1], fp[2], fp[3]);
        *(float4*)(omrow + i) = make_float4(fo[0], fo[1], fo[2], fo[3]);
    }
}

// One block per row. Tracks (value-key, original index) pairs so top-p can
// split DUPLICATE boundary values exactly like the reference's stable
// positional sort does.
__global__ __launch_bounds__(256) void k_rowsel(
    const float* __restrict__ logits,
    const unsigned* __restrict__ bitP, const unsigned* __restrict__ bitO,
    const float* __restrict__ rep, const float* __restrict__ pres,
    const float* __restrict__ temp,
    const int* __restrict__ topk, const float* __restrict__ topp,
    float4* __restrict__ params, int* __restrict__ idxc)
{
    __shared__ unsigned h[4096];
    __shared__ unsigned long long list[LCAP];
    __shared__ unsigned long long kv[256];
    __shared__ unsigned sA[256];
    __shared__ int s_bsel;
    __shared__ unsigned s_n, s_prefix, s_krem, s_kcnt;
    int r = blockIdx.x;
    int t = threadIdx.x;
    float rp = rep[r], pp = pres[r];
    float tt = temp[r]; tt = (tt < 1e-5f) ? 1.0f : tt;
    const float* lrow = logits + (size_t)r * V;
    const unsigned* bp = bitP + r * WPR;
    const unsigned* bo = bitO + r * WPR;

    for (int i = t; i < 4096; i += 256) h[i] = 0u;
    __syncthreads();
    // pass 1: 4096-bin histogram of transformed-value keys
    for (int i = t * 4; i < V; i += 1024) {
        float4 x = *(const float4*)(lrow + i);
        unsigned wp = bp[i >> 5], wo = bo[i >> 5];
        int sh = i & 31;
        float xs[4] = {x.x, x.y, x.z, x.w};
#pragma unroll
        for (int j = 0; j < 4; j++) {
            int p = (wp >> (sh + j)) & 1;
            int o = (wo >> (sh + j)) & 1;
            float l = xform(xs[j], p, o, rp, pp, tt);
            atomicAdd(&h[key_of(l) >> 20], 1u);
        }
    }
    __syncthreads();
    // suffix scan over 256 chunks of 16 bins; find bin of the R_SEL-th largest
    unsigned cs = 0;
#pragma unroll
    for (int j = 0; j < 16; j++) cs += h[t * 16 + j];
    sA[t] = cs;
    __syncthreads();
    unsigned v = cs;
    for (int st = 1; st < 256; st <<= 1) {
        unsigned add = (t + st < 256) ? sA[t + st] : 0u;
        __syncthreads();
        v += add; sA[t] = v;
        __syncthreads();
    }
    unsigned Snext = (t < 255) ? sA[t + 1] : 0u;
    if (sA[t] >= (unsigned)R_SEL && Snext < (unsigned)R_SEL) {
        unsigned run = Snext;
        int b = t * 16;
        for (int j = 15; j >= 0; j--) {
            run += h[t * 16 + j];
            if (run >= (unsigned)R_SEL) { b = t * 16 + j; break; }
        }
        s_bsel = b;
    }
    if (t == 0) s_n = 0u;
    __syncthreads();
    int bsel = s_bsel;
    // pass 2: gather (key<<32)|idx for all elements in bins >= bsel
    for (int i = t * 4; i < V; i += 1024) {
        float4 x = *(const float4*)(lrow + i);
        unsigned wp = bp[i >> 5], wo = bo[i >> 5];
        int sh = i & 31;
        float xs[4] = {x.x, x.y, x.z, x.w};
#pragma unroll
        for (int j = 0; j < 4; j++) {
            int p = (wp >> (sh + j)) & 1;
            int o = (wo >> (sh + j)) & 1;
            float l = xform(xs[j], p, o, rp, pp, tt);
            unsigned key = key_of(l);
            if ((int)(key >> 20) >= bsel) {
                unsigned pos = atomicAdd(&s_n, 1u);
                if (pos < (unsigned)LCAP)
                    list[pos] = ((unsigned long long)key << 32) | (unsigned)(i + j);
            }
        }
    }
    __syncthreads();
    int n = (int)min(s_n, (unsigned)LCAP);
    int k = topk[r]; k = max(1, min(k, 127));
    if (t == 0) { s_prefix = 0u; s_krem = (unsigned)k; }
    __syncthreads();
    // 4-round radix select of k-th largest VALUE key (upper 32 bits)
    unsigned* rh = h;
    unsigned* rsuf = h + 256;
    for (int round = 3; round >= 0; round--) {
        int shift = round * 8;
        unsigned prefix = s_prefix;
        unsigned krem = s_krem;
        unsigned maskAbove = (round == 3) ? 0u : (0xFFFFFFFFu << (shift + 8));
        rh[t] = 0u;
        __syncthreads();
        for (int i = t; i < n; i += 256) {
            unsigned key = (unsigned)(list[i] >> 32);
            if ((key & maskAbove) == (prefix & maskAbove))
                atomicAdd(&rh[(key >> shift) & 255u], 1u);
        }
        __syncthreads();
        unsigned vv = rh[t];
        rsuf[t] = vv;
        __syncthreads();
        for (int st = 1; st < 256; st <<= 1) {
            unsigned add = (t + st < 256) ? rsuf[t + st] : 0u;
            __syncthreads();
            vv += add; rsuf[t] = vv;
            __syncthreads();
        }
        unsigned Sx = (t < 255) ? rsuf[t + 1] : 0u;
        if (rsuf[t] >= krem && Sx < krem) {
            s_prefix = prefix | ((unsigned)t << shift);
            s_krem = krem - Sx;
        }
        __syncthreads();
    }
    unsigned thrkey = s_prefix;   // k-th largest value key; ties all kept
    if (t == 0) s_kcnt = 0u;
    __syncthreads();
    for (int i = t; i < n; i += 256) {
        if ((unsigned)(list[i] >> 32) >= thrkey) {
            unsigned pos = atomicAdd(&s_kcnt, 1u);
            if (pos < 256u) kv[pos] = list[i];
        }
    }
    __syncthreads();
    int K = (int)min(s_kcnt, 256u);
    if (t >= K) kv[t] = 0ULL;     // sorts last (real keys are large)
    __syncthreads();
    // bitonic sort 256 uint64 descending: (value desc, idx desc) == exact
    // descending view of the reference's stable ascending argsort
    for (unsigned k2 = 2; k2 <= 256; k2 <<= 1) {
        for (unsigned j2 = k2 >> 1; j2 > 0; j2 >>= 1) {
            unsigned ixj = (unsigned)t ^ j2;
            if (ixj > (unsigned)t) {
                unsigned long long a = kv[t], b = kv[ixj];
                bool descBlock = (((unsigned)t & k2) == 0u);
                bool doSwap = descBlock ? (a < b) : (a > b);
                if (doSwap) { kv[t] = b; kv[ixj] = a; }
            }
            __syncthreads();
        }
    }
    // serial tail: positional top-p on exact f64 csum; boundary entry gives
    // (value, idx) cut so duplicate boundary values split exactly as ref
    if (t == 0) {
        float Mxf = key_inv((unsigned)(kv[0] >> 32));
        double MxD = (double)Mxf;
        double e_tinyD = exp((double)FP16_TINY - MxD);
        double S = 0.0;
        for (int i = K - 1; i >= 0; i--)
            S += exp((double)key_inv((unsigned)(kv[i] >> 32)) - MxD);
        double Z1 = (double)(V - K) * e_tinyD + S;
        double base = (double)(V - K) * e_tinyD / Z1;
        double thresh = 1.0 - (double)topp[r];
        double dd = base;
        int ns = K;
        for (int a = 0; a <= K - 2; a++) {      // ascending positions, excl. top
            int i = K - 1 - a;
            dd += exp((double)key_inv((unsigned)(kv[i] >> 32)) - MxD) / Z1;
            if (dd <= thresh) ns--;
        }
        // survivors = kv[0 .. ns-1]; boundary = kv[ns-1]
        unsigned bkey = (unsigned)(kv[ns - 1] >> 32);
        float v_b = key_inv(bkey);
        unsigned idx_cut = (unsigned)(kv[ns - 1] & 0xFFFFFFFFu);
        float tiny_e = expf(FP16_TINY - Mxf);
        double S2 = 0.0;
        for (int i = 0; i < ns; i++)
            S2 += (double)expf(key_inv((unsigned)(kv[i] >> 32)) - Mxf);
        double Z2 = (double)(V - ns) * (double)tiny_e + S2;
        float invZ2 = (float)(1.0 / Z2);
        params[r] = make_float4(v_b, Mxf, invZ2, tiny_e * invZ2);
        idxc[r] = (int)idx_cut;
    }
}

__global__ __launch_bounds__(256) void k_final(
    const float* __restrict__ logits,
    const unsigned* __restrict__ bitP, const unsigned* __restrict__ bitO,
    const float* __restrict__ rep, const float* __restrict__ pres,
    const float* __restrict__ temp,
    const float4* __restrict__ params, const int* __restrict__ idxc,
    float* __restrict__ probs)
{
    int r = blockIdx.y;
    int c0 = blockIdx.x * (ITERS * 1024);
    int t = threadIdx.x;
    float rp = rep[r], pp = pres[r];
    float tt = temp[r]; tt = (tt < 1e-5f) ? 1.0f : tt;
    float4 pr = params[r];
    float v_b = pr.x, Mx = pr.y, invZ2 = pr.z, ptiny = pr.w;
    unsigned idx_cut = (unsigned)idxc[r];
    const float* lrow = logits + (size_t)r * V;
    float* orow = probs + (size_t)r * V;
    const unsigned* bp = bitP + r * WPR;
    const unsigned* bo = bitO + r * WPR;
#pragma unroll
    for (int it = 0; it < ITERS; it++) {
        int i = c0 + it * 1024 + t * 4;
        float4 x = *(const float4*)(lrow + i);
        unsigned wp = bp[i >> 5], wo = bo[i >> 5];
        int sh = i & 31;
        float xs[4] = {x.x, x.y, x.z, x.w};
        float res[4];
#pragma unroll
        for (int j = 0; j < 4; j++) {
            int p = (wp >> (sh + j)) & 1;
            int o = (wo >> (sh + j)) & 1;
            float l = xform(xs[j], p, o, rp, pp, tt);
            bool keep = (l > v_b) || (l == v_b && (unsigned)(i + j) >= idx_cut);
            res[j] = keep ? (expf(l - Mx) * invZ2) : ptiny;
        }
        *(float4*)(orow + i) = make_float4(res[0], res[1], res[2], res[3]);
    }
}

extern "C" void kernel_launch(void* const* d_in, const int* in_sizes, int n_in,
                              void* d_out, int out_size, void* d_ws, size_t ws_size,
                              hipStream_t stream) {
    const float* logits = (const float*)d_in[0];
    const int* ptok     = (const int*)d_in[1];
    const int* otok     = (const int*)d_in[2];
    const float* pres   = (const float*)d_in[3];
    // d_in[4] = frequency_penalties: computed but never applied in reference
    const float* rep    = (const float*)d_in[5];
    const float* temp   = (const float*)d_in[6];
    const int* topk     = (const int*)d_in[7];
    const float* topp   = (const float*)d_in[8];

    float* out_probs = (float*)d_out;
    float* out_pm = out_probs + (size_t)B * V;
    float* out_om = out_pm + (size_t)B * V;

    unsigned* ws0 = (unsigned*)d_ws;
    float4* params = (float4*)d_ws;          // 128 * 16B at ws base
    int* idxc = (int*)(ws0 + 512);           // 128 ints
    unsigned* bitP = ws0 + 768;
    unsigned* bitO = bitP + B * WPR;

    k_zero<<<256, 256, 0, stream>>>(bitP, 2 * B * WPR);

    int ntok = B * PL + B * OL;
    k_scatter<<<(ntok + 255) / 256, 256, 0, stream>>>(ptok, otok, bitP, bitO);

    dim3 g(BPR, B);
    k_masks<<<g, 256, 0, stream>>>(bitP, bitO, out_pm, out_om);
    k_rowsel<<<B, 256, 0, stream>>>(logits, bitP, bitO, rep, pres, temp,
                                    topk, topp, params, idxc);
    k_final<<<g, 256, 0, stream>>>(logits, bitP, bitO, rep, pres, temp,
                                   params, idxc, out_probs);
}